// Round 1
// baseline (111.295 us; speedup 1.0000x reference)
//
#include <hip/hip_runtime.h>
#include <hip/hip_bf16.h>

// BilinearPooling: out[b, i*2048+j] = xp[b,i]*yp[b,j] / max(||xp_b||*||yp_b||, eps)
// where xp = x @ W^T, yp = y @ W^T.  B=32, D_IN=1024, D_OUT=2048, fp32.
// ||outer(u,v)||_F = ||u||*||v||  ->  never materialize z before normalizing.

#define BROWS 64       // stacked rows: 32 x-rows then 32 y-rows
#define DIN   1024
#define DOUT  2048
#define OTILE 64
#define LDA   132      // padded LDS leading dim (floats)
#define ITILE 16
#define EPS_N 1e-12f

// ---------------- Kernel 1: partial GEMM  proj_partial[ks][r][o] ----------------
// Block = 256 threads, computes a [64 rows x 64 cols] tile over K-chunk DIN/KS.
// Thread t: tr = t/16, tc = t%16; owns rows (tr + 16*rr), cols (o0 + tc + 16*cc),
// rr,cc in [0,4). Row mappings keep wave LDS reads at <=2-way bank conflicts.
template <int KS>
__global__ __launch_bounds__(256) void gemm_partial_k(
    const float* __restrict__ x, const float* __restrict__ y,
    const float* __restrict__ W, float* __restrict__ part)
{
    constexpr int KCHUNK = DIN / KS;     // K elements this block accumulates
    constexpr int NSTAGE = KCHUNK / 128; // 128-float K sub-tiles staged in LDS

    const int o0 = blockIdx.x * OTILE;
    const int ks = blockIdx.y;
    const int t  = threadIdx.x;

    __shared__ float As[BROWS * LDA];
    __shared__ float Bs[OTILE * LDA];

    const int tr = t >> 4;
    const int tc = t & 15;

    float acc[4][4];
#pragma unroll
    for (int a = 0; a < 4; ++a)
#pragma unroll
        for (int b = 0; b < 4; ++b) acc[a][b] = 0.f;

    for (int st = 0; st < NSTAGE; ++st) {
        const int k0 = ks * KCHUNK + st * 128;
        if (st) __syncthreads();
        // stage A: 64 rows x 128 floats = 2048 float4, 8 per thread
#pragma unroll
        for (int i = 0; i < 8; ++i) {
            int li = t + i * 256;
            int r  = li >> 5;          // 32 float4 per row
            int c4 = li & 31;
            const float* src =
                (r < 32 ? x + (size_t)r * DIN : y + (size_t)(r - 32) * DIN)
                + k0 + c4 * 4;
            *(float4*)&As[r * LDA + c4 * 4] = *(const float4*)src;
        }
        // stage B: W rows o0..o0+63
#pragma unroll
        for (int i = 0; i < 8; ++i) {
            int li = t + i * 256;
            int r  = li >> 5;
            int c4 = li & 31;
            *(float4*)&Bs[r * LDA + c4 * 4] =
                *(const float4*)(W + (size_t)(o0 + r) * DIN + k0 + c4 * 4);
        }
        __syncthreads();

#pragma unroll 8
        for (int k4 = 0; k4 < 32; ++k4) {
            const int k = k4 * 4;
            float4 av[4], bv[4];
#pragma unroll
            for (int rr = 0; rr < 4; ++rr)
                av[rr] = *(float4*)&As[(tr + 16 * rr) * LDA + k];
#pragma unroll
            for (int cc = 0; cc < 4; ++cc)
                bv[cc] = *(float4*)&Bs[(tc + 16 * cc) * LDA + k];
#pragma unroll
            for (int rr = 0; rr < 4; ++rr)
#pragma unroll
                for (int cc = 0; cc < 4; ++cc) {
                    acc[rr][cc] = fmaf(av[rr].x, bv[cc].x, acc[rr][cc]);
                    acc[rr][cc] = fmaf(av[rr].y, bv[cc].y, acc[rr][cc]);
                    acc[rr][cc] = fmaf(av[rr].z, bv[cc].z, acc[rr][cc]);
                    acc[rr][cc] = fmaf(av[rr].w, bv[cc].w, acc[rr][cc]);
                }
        }
    }

#pragma unroll
    for (int rr = 0; rr < 4; ++rr) {
        const int r = tr + 16 * rr;
#pragma unroll
        for (int cc = 0; cc < 4; ++cc) {
            const int o = o0 + tc + 16 * cc;
            part[((size_t)(ks * BROWS + r)) * DOUT + o] = acc[rr][cc];
        }
    }
}

// ---------------- Kernel 2: reduce partials + row norms ----------------
template <int KS>
__global__ __launch_bounds__(256) void reduce_rows_k(
    const float* __restrict__ part, float* __restrict__ proj,
    float* __restrict__ norms)
{
    const int r = blockIdx.x;
    const int t = threadIdx.x;
    float ss = 0.f;
#pragma unroll
    for (int it = 0; it < 2; ++it) {
        const int j4 = t + it * 256;   // 512 float4 per row
        float4 s = make_float4(0.f, 0.f, 0.f, 0.f);
#pragma unroll
        for (int ks = 0; ks < KS; ++ks) {
            float4 v = *(const float4*)&part[((size_t)(ks * BROWS + r)) * DOUT + j4 * 4];
            s.x += v.x; s.y += v.y; s.z += v.z; s.w += v.w;
        }
        *(float4*)&proj[(size_t)r * DOUT + j4 * 4] = s;
        ss += s.x * s.x + s.y * s.y + s.z * s.z + s.w * s.w;
    }
    // wave reduce (wave = 64)
#pragma unroll
    for (int m = 32; m >= 1; m >>= 1) ss += __shfl_xor(ss, m, 64);
    __shared__ float red[4];
    const int lane = t & 63, wv = t >> 6;
    if (lane == 0) red[wv] = ss;
    __syncthreads();
    if (t == 0) norms[r] = sqrtf(red[0] + red[1] + red[2] + red[3]);
}

// ---------------- Kernel 3: streamed outer-product write ----------------
__global__ __launch_bounds__(256) void outer_write(
    const float* __restrict__ proj, const float* __restrict__ norms,
    float* __restrict__ out)
{
    const int b  = blockIdx.y;
    const int i0 = blockIdx.x * ITILE;
    const int t  = threadIdx.x;

    const float* yrow = proj + (size_t)(32 + b) * DOUT;
    const float4 y0 = *(const float4*)&yrow[t * 4];
    const float4 y1 = *(const float4*)&yrow[(t + 256) * 4];
    const float  s  = 1.0f / fmaxf(norms[b] * norms[32 + b], EPS_N);

    const float* xrow = proj + (size_t)b * DOUT + i0;
    float4* outp = (float4*)out + ((size_t)b * DOUT + i0) * (DOUT / 4);

#pragma unroll
    for (int i = 0; i < ITILE; ++i) {
        const float xv = xrow[i] * s;
        float4 o0v = make_float4(xv * y0.x, xv * y0.y, xv * y0.z, xv * y0.w);
        float4 o1v = make_float4(xv * y1.x, xv * y1.y, xv * y1.z, xv * y1.w);
        outp[(size_t)i * (DOUT / 4) + t]       = o0v;
        outp[(size_t)i * (DOUT / 4) + t + 256] = o1v;
    }
}

// ---------------- launch ----------------
template <int KS>
static void run_pipeline(const float* x, const float* y, const float* W,
                         float* out, float* ws, hipStream_t stream)
{
    float* part  = ws;                                   // KS*64*2048 floats
    float* proj  = part + (size_t)KS * BROWS * DOUT;     // 64*2048
    float* norms = proj + (size_t)BROWS * DOUT;          // 64
    gemm_partial_k<KS><<<dim3(DOUT / OTILE, KS), 256, 0, stream>>>(x, y, W, part);
    reduce_rows_k<KS><<<BROWS, 256, 0, stream>>>(part, proj, norms);
    outer_write<<<dim3(DOUT / ITILE, 32), 256, 0, stream>>>(proj, norms, out);
}

extern "C" void kernel_launch(void* const* d_in, const int* in_sizes, int n_in,
                              void* d_out, int out_size, void* d_ws, size_t ws_size,
                              hipStream_t stream)
{
    const float* x = (const float*)d_in[0];
    const float* y = (const float*)d_in[1];
    const float* W = (const float*)d_in[2];
    float* out = (float*)d_out;
    float* ws  = (float*)d_ws;

    const size_t need = [](int ks) {
        return ((size_t)ks * BROWS * DOUT + (size_t)BROWS * DOUT + 64) * sizeof(float);
    }(8);
    const size_t need4 = ((size_t)4 * BROWS * DOUT + (size_t)BROWS * DOUT + 64) * sizeof(float);

    if (ws_size >= need)
        run_pipeline<8>(x, y, W, out, ws, stream);
    else if (ws_size >= need4)
        run_pipeline<4>(x, y, W, out, ws, stream);
    else
        run_pipeline<1>(x, y, W, out, ws, stream);
}

// Round 3
// 110.418 us; speedup vs baseline: 1.0079x; 1.0079x over previous
//
#include <hip/hip_runtime.h>
#include <hip/hip_bf16.h>

// BilinearPooling: out[b, i*2048+j] = xp[b,i]*yp[b,j] / max(||xp_b||*||yp_b||, eps)
// where xp = x @ W^T, yp = y @ W^T.  B=32, D_IN=1024, D_OUT=2048, fp32.
// ||outer(u,v)||_F = ||u||*||v||  ->  never materialize z before normalizing.
// Roofline: 512 MiB of pure streaming writes @ ~6.7 TB/s (measured fill rate) ~= 80 us.

#define BROWS 64       // stacked rows: 32 x-rows then 32 y-rows
#define DIN   1024
#define DOUT  2048
#define OTILE 64
#define LDA   132      // padded LDS leading dim (floats)
#define ITILE 32       // 2048 blocks = exactly 8 blocks/CU x 256 CU resident
#define EPS_N 1e-12f

typedef float fx4 __attribute__((ext_vector_type(4)));  // native vec for nontemporal stores

// ---------------- Kernel 1: partial GEMM  proj_partial[ks][r][o] ----------------
template <int KS>
__global__ __launch_bounds__(256) void gemm_partial_k(
    const float* __restrict__ x, const float* __restrict__ y,
    const float* __restrict__ W, float* __restrict__ part)
{
    constexpr int KCHUNK = DIN / KS;
    constexpr int NSTAGE = KCHUNK / 128;

    const int o0 = blockIdx.x * OTILE;
    const int ks = blockIdx.y;
    const int t  = threadIdx.x;

    __shared__ float As[BROWS * LDA];
    __shared__ float Bs[OTILE * LDA];

    const int tr = t >> 4;
    const int tc = t & 15;

    float acc[4][4];
#pragma unroll
    for (int a = 0; a < 4; ++a)
#pragma unroll
        for (int b = 0; b < 4; ++b) acc[a][b] = 0.f;

    for (int st = 0; st < NSTAGE; ++st) {
        const int k0 = ks * KCHUNK + st * 128;
        if (st) __syncthreads();
#pragma unroll
        for (int i = 0; i < 8; ++i) {
            int li = t + i * 256;
            int r  = li >> 5;
            int c4 = li & 31;
            const float* src =
                (r < 32 ? x + (size_t)r * DIN : y + (size_t)(r - 32) * DIN)
                + k0 + c4 * 4;
            *(float4*)&As[r * LDA + c4 * 4] = *(const float4*)src;
        }
#pragma unroll
        for (int i = 0; i < 8; ++i) {
            int li = t + i * 256;
            int r  = li >> 5;
            int c4 = li & 31;
            *(float4*)&Bs[r * LDA + c4 * 4] =
                *(const float4*)(W + (size_t)(o0 + r) * DIN + k0 + c4 * 4);
        }
        __syncthreads();

#pragma unroll 8
        for (int k4 = 0; k4 < 32; ++k4) {
            const int k = k4 * 4;
            float4 av[4], bv[4];
#pragma unroll
            for (int rr = 0; rr < 4; ++rr)
                av[rr] = *(float4*)&As[(tr + 16 * rr) * LDA + k];
#pragma unroll
            for (int cc = 0; cc < 4; ++cc)
                bv[cc] = *(float4*)&Bs[(tc + 16 * cc) * LDA + k];
#pragma unroll
            for (int rr = 0; rr < 4; ++rr)
#pragma unroll
                for (int cc = 0; cc < 4; ++cc) {
                    acc[rr][cc] = fmaf(av[rr].x, bv[cc].x, acc[rr][cc]);
                    acc[rr][cc] = fmaf(av[rr].y, bv[cc].y, acc[rr][cc]);
                    acc[rr][cc] = fmaf(av[rr].z, bv[cc].z, acc[rr][cc]);
                    acc[rr][cc] = fmaf(av[rr].w, bv[cc].w, acc[rr][cc]);
                }
        }
    }

#pragma unroll
    for (int rr = 0; rr < 4; ++rr) {
        const int r = tr + 16 * rr;
#pragma unroll
        for (int cc = 0; cc < 4; ++cc) {
            const int o = o0 + tc + 16 * cc;
            part[((size_t)(ks * BROWS + r)) * DOUT + o] = acc[rr][cc];
        }
    }
}

// ---------------- Kernel 2: reduce partials + row norms ----------------
template <int KS>
__global__ __launch_bounds__(256) void reduce_rows_k(
    const float* __restrict__ part, float* __restrict__ proj,
    float* __restrict__ norms)
{
    const int r = blockIdx.x;
    const int t = threadIdx.x;
    float ss = 0.f;
#pragma unroll
    for (int it = 0; it < 2; ++it) {
        const int j4 = t + it * 256;
        float4 s = make_float4(0.f, 0.f, 0.f, 0.f);
#pragma unroll
        for (int ks = 0; ks < KS; ++ks) {
            float4 v = *(const float4*)&part[((size_t)(ks * BROWS + r)) * DOUT + j4 * 4];
            s.x += v.x; s.y += v.y; s.z += v.z; s.w += v.w;
        }
        *(float4*)&proj[(size_t)r * DOUT + j4 * 4] = s;
        ss += s.x * s.x + s.y * s.y + s.z * s.z + s.w * s.w;
    }
#pragma unroll
    for (int m = 32; m >= 1; m >>= 1) ss += __shfl_xor(ss, m, 64);
    __shared__ float red[4];
    const int lane = t & 63, wv = t >> 6;
    if (lane == 0) red[wv] = ss;
    __syncthreads();
    if (t == 0) norms[r] = sqrtf(red[0] + red[1] + red[2] + red[3]);
}

// ---------------- Kernel 3: streamed outer-product write ----------------
__global__ __launch_bounds__(256) void outer_write(
    const float* __restrict__ proj, const float* __restrict__ norms,
    float* __restrict__ out)
{
    const int b  = blockIdx.y;
    const int i0 = blockIdx.x * ITILE;
    const int t  = threadIdx.x;

    const float* yrow = proj + (size_t)(32 + b) * DOUT;
    const float4 y0 = *(const float4*)&yrow[t * 4];
    const float4 y1 = *(const float4*)&yrow[(t + 256) * 4];
    const float  s  = 1.0f / fmaxf(norms[b] * norms[32 + b], EPS_N);

    const float* xrow = proj + (size_t)b * DOUT + i0;
    fx4* outp = (fx4*)out + ((size_t)b * DOUT + i0) * (DOUT / 4) + t;

#pragma unroll
    for (int i = 0; i < ITILE; ++i) {
        const float xv = xrow[i] * s;
        fx4 o0v = { xv * y0.x, xv * y0.y, xv * y0.z, xv * y0.w };
        fx4 o1v = { xv * y1.x, xv * y1.y, xv * y1.z, xv * y1.w };
        __builtin_nontemporal_store(o0v, outp);
        __builtin_nontemporal_store(o1v, outp + 256);
        outp += DOUT / 4;
    }
}

// ---------------- launch ----------------
template <int KS>
static void run_pipeline(const float* x, const float* y, const float* W,
                         float* out, float* ws, hipStream_t stream)
{
    float* part  = ws;
    float* proj  = part + (size_t)KS * BROWS * DOUT;
    float* norms = proj + (size_t)BROWS * DOUT;
    gemm_partial_k<KS><<<dim3(DOUT / OTILE, KS), 256, 0, stream>>>(x, y, W, part);
    reduce_rows_k<KS><<<BROWS, 256, 0, stream>>>(part, proj, norms);
    outer_write<<<dim3(DOUT / ITILE, 32), 256, 0, stream>>>(proj, norms, out);
}

extern "C" void kernel_launch(void* const* d_in, const int* in_sizes, int n_in,
                              void* d_out, int out_size, void* d_ws, size_t ws_size,
                              hipStream_t stream)
{
    const float* x = (const float*)d_in[0];
    const float* y = (const float*)d_in[1];
    const float* W = (const float*)d_in[2];
    float* out = (float*)d_out;
    float* ws  = (float*)d_ws;

    const size_t need8 = ((size_t)8 * BROWS * DOUT + (size_t)BROWS * DOUT + 64) * sizeof(float);
    const size_t need4 = ((size_t)4 * BROWS * DOUT + (size_t)BROWS * DOUT + 64) * sizeof(float);

    if (ws_size >= need8)
        run_pipeline<8>(x, y, W, out, ws, stream);
    else if (ws_size >= need4)
        run_pipeline<4>(x, y, W, out, ws, stream);
    else
        run_pipeline<1>(x, y, W, out, ws, stream);
}